// Round 5
// baseline (11919.427 us; speedup 1.0000x reference)
//
#include <hip/hip_runtime.h>
#include <stdint.h>

#define B_ 32
#define T_ 2048
#define H_ 256
#define M_ 64
#define L_ 256
#define G4_ 1024     // 4*H gate rows

#define NG_ 8        // batch groups (4 batches each)
#define NSL_ 16      // hidden slices per group
#define EPT_ 16      // h elements per slice
#define RING_ 8      // ring slots; block skew <=1 so reuse distance 8 is safe

__device__ __forceinline__ float sig_fast(float x){ return 1.f/(1.f+__expf(-x)); }
__device__ __forceinline__ float tanh_fast(float x){ return 2.f/(1.f+__expf(-2.f*x)) - 1.f; }
__device__ __forceinline__ float dot4(float4 a, float4 b){
  return fmaf(a.x,b.x, fmaf(a.y,b.y, fmaf(a.z,b.z, a.w*b.w)));
}

// ---------------- prep kernels ----------------
__global__ void prep_wdc(const float* __restrict__ a, const float* __restrict__ b,
                         float* __restrict__ o){
  int i = blockIdx.x*256 + threadIdx.x;
  o[i] = a[i] + b[i];
}

__global__ void prep_small(const float* __restrict__ Wp, const float* __restrict__ bp,
                           const float* __restrict__ Wihe, const float* __restrict__ bihe,
                           const float* __restrict__ bhhe, const float* __restrict__ bihd,
                           const float* __restrict__ bhhd, const float* __restrict__ Wq,
                           float* __restrict__ Wc0, float* __restrict__ Wc1,
                           float* __restrict__ bc, float* __restrict__ bdc,
                           float* __restrict__ WqT){
  int idx = blockIdx.x*256 + threadIdx.x;
  if (idx < 16384){                 // WqT[m][k] = Wq[k][m]
    int m = idx >> 8, k = idx & 255;
    WqT[m*256 + k] = Wq[k*64 + m];
  } else if (idx < 16384 + 1024){   // fused input coeffs per gate row
    int j = idx - 16384;
    const float* wr = Wihe + j*256;
    float a0=0.f, a1=0.f, ab=0.f;
    for (int e=0;e<256;e++){
      float w = wr[e];
      a0 = fmaf(Wp[e],     w, a0);
      a1 = fmaf(Wp[256+e], w, a1);
      ab = fmaf(bp[e],     w, ab);
    }
    Wc0[j] = a0; Wc1[j] = a1;
    bc[j]  = ab + bihe[j] + bhhe[j];
    bdc[j] = bihd[j] + bhhd[j];
  }
}

// ---------------- encoder LSTM (persistent; flag + one-shot data exchange) ----------------
__global__ __launch_bounds__(1024) void enc_kernel(
    const float* __restrict__ seq, const int* __restrict__ slen,
    const float* __restrict__ Whh,
    const float* __restrict__ Wc0, const float* __restrict__ Wc1,
    const float* __restrict__ bc,
    float* __restrict__ h_all, float* __restrict__ cT,
    unsigned long long* __restrict__ rde, int* __restrict__ flge)
{
  const int tid = threadIdx.x;
  const int grp = blockIdx.x & 7, slice = blockIdx.x >> 3;
  const int rp = tid >> 4, kc = tid & 15;
  const int j = ((rp >> 4) << 8) + slice*EPT_ + (rp & 15);   // gate*256 + slice*16 + elem
  float4 w0 = *(const float4*)(Whh + (size_t)j*256 +   0 + kc*4);
  float4 w1 = *(const float4*)(Whh + (size_t)j*256 +  64 + kc*4);
  float4 w2 = *(const float4*)(Whh + (size_t)j*256 + 128 + kc*4);
  float4 w3 = *(const float4*)(Whh + (size_t)j*256 + 192 + kc*4);
  float c0 = Wc0[j], c1 = Wc1[j], cbv = bc[j];

  __shared__ float hbuf[4][256];
  __shared__ float sbuf[4][2];
  __shared__ float gbuf[4][64];
  __shared__ float xbuf[4][16];    // update staging for the 4 writer threads

  const int ub = tid >> 4, ue = tid & 15;       // updater mapping (tid<64)
  float creg = 0.f;
  int myb = 0, mylen = -1;
  if (tid < 64){ myb = grp + 8*ub; mylen = slen[myb]; }

  const int tb = tid >> 7, kp = tid & 127;      // loader mapping (tid<512)
  const int ps = (tid - 64) >> 2, pb = (tid - 64) & 3;  // poller mapping (64<=tid<128)

  for (int i = 0; i < T_; ++i){
    const int slot = (i - 1) & (RING_ - 1);
    // ---- phase 1a: update for step i-1 (uses gbuf from previous compute) ----
    if (i > 0 && tid < 64){
      float gi = gbuf[ub][      ue];
      float gf = gbuf[ub][16 + ue];
      float gg = gbuf[ub][32 + ue];
      float go = gbuf[ub][48 + ue];
      creg = sig_fast(gf)*creg + sig_fast(gi)*tanh_fast(gg);
      float h = sig_fast(go)*tanh_fast(creg);
      xbuf[ub][ue] = h;                              // for writers
      hbuf[ub][slice*EPT_ + ue] = h;                 // own slice: LDS short-circuit
      h_all[((size_t)(i-1)*B_ + myb)*H_ + slice*EPT_ + ue] = h;  // plain, off critical path
      if (i == mylen) cT[myb*H_ + slice*EPT_ + ue] = creg;
    }
    __syncthreads();  // Bx: xbuf visible to writers

    // ---- phase 1b: 4 writers push data + release per-(slice,batch) flag ----
    if (i > 0 && tid < 4){
      unsigned long long* dst = rde + (((size_t)slot*NG_ + grp)*4 + tid)*128 + slice*8;
      const unsigned long long* xs = (const unsigned long long*)xbuf[tid];
#pragma unroll
      for (int k = 0; k < 8; ++k)
        __hip_atomic_store(dst + k, xs[k], __ATOMIC_RELAXED, __HIP_MEMORY_SCOPE_AGENT);
      int* fp = flge + ((((size_t)slot*NG_ + grp)*NSL_ + slice)*4 + tid)*16;
      __hip_atomic_store(fp, i, __ATOMIC_RELEASE, __HIP_MEMORY_SCOPE_AGENT);
    }
    // ---- phase 2: 64 pollers wait for the 15 remote slices' flags ----
    if (i > 0 && tid >= 64 && tid < 128 && ps != slice){
      const int* fp = flge + ((((size_t)slot*NG_ + grp)*NSL_ + ps)*4 + pb)*16;
      while (__hip_atomic_load(fp, __ATOMIC_RELAXED, __HIP_MEMORY_SCOPE_AGENT) != i) {}
      __builtin_amdgcn_fence(__ATOMIC_ACQUIRE, "agent");
    }
    // ---- per-step seq inputs ----
    if (tid >= 128 && tid < 136){
      int b4 = (tid - 128) >> 1, ix = (tid - 128) & 1;
      sbuf[b4][ix] = seq[((size_t)(grp + 8*b4)*T_ + i)*2 + ix];
    }
    __syncthreads();  // B0: flags observed; safe to one-shot load

    // ---- phase 3: one-shot data load (512 threads x 8B) ----
    if (tid < 512){
      if (i == 0){
        *(float2*)&hbuf[tb][kp*2] = make_float2(0.f, 0.f);
      } else if ((kp >> 3) != slice){
        unsigned long long v = __hip_atomic_load(
            rde + (((size_t)slot*NG_ + grp)*4 + tb)*128 + kp,
            __ATOMIC_RELAXED, __HIP_MEMORY_SCOPE_AGENT);
        *(float2*)&hbuf[tb][kp*2] = __builtin_bit_cast(float2, v);
      }
    }
    __syncthreads();  // B1: hbuf ready

    // ---- compute gates_i ----
#pragma unroll
    for (int b4 = 0; b4 < 4; ++b4){
      float4 h0 = *(const float4*)&hbuf[b4][       kc*4];
      float4 h1 = *(const float4*)&hbuf[b4][ 64 + kc*4];
      float4 h2 = *(const float4*)&hbuf[b4][128 + kc*4];
      float4 h3 = *(const float4*)&hbuf[b4][192 + kc*4];
      float a = dot4(w0,h0) + dot4(w1,h1) + dot4(w2,h2) + dot4(w3,h3);
#pragma unroll
      for (int off = 1; off < 16; off <<= 1) a += __shfl_xor(a, off);
      if (kc == 0)
        gbuf[b4][rp] = fmaf(sbuf[b4][0], c0, fmaf(sbuf[b4][1], c1, a + cbv));
    }
    __syncthreads();  // B2: gbuf ready for next iteration's update
  }

  // final update for step T-1 (no consumers via ring; h_all/cT only)
  if (tid < 64){
    float gi = gbuf[ub][      ue];
    float gf = gbuf[ub][16 + ue];
    float gg = gbuf[ub][32 + ue];
    float go = gbuf[ub][48 + ue];
    creg = sig_fast(gf)*creg + sig_fast(gi)*tanh_fast(gg);
    float h = sig_fast(go)*tanh_fast(creg);
    h_all[((size_t)(T_-1)*B_ + myb)*H_ + slice*EPT_ + ue] = h;
    if (mylen == T_) cT[myb*H_ + slice*EPT_ + ue] = creg;
  }
}

// ---------------- decoder LSTM (x == h, folded weights) ----------------
__global__ __launch_bounds__(1024) void dec_kernel(
    const int* __restrict__ slen,
    const float* __restrict__ Wdc, const float* __restrict__ bdc,
    const float* __restrict__ h_all, const float* __restrict__ cT,
    float* __restrict__ h2_all,
    unsigned long long* __restrict__ rdd, int* __restrict__ flgd)
{
  const int tid = threadIdx.x;
  const int grp = blockIdx.x & 7, slice = blockIdx.x >> 3;
  const int rp = tid >> 4, kc = tid & 15;
  const int j = ((rp >> 4) << 8) + slice*EPT_ + (rp & 15);
  float4 w0 = *(const float4*)(Wdc + (size_t)j*256 +   0 + kc*4);
  float4 w1 = *(const float4*)(Wdc + (size_t)j*256 +  64 + kc*4);
  float4 w2 = *(const float4*)(Wdc + (size_t)j*256 + 128 + kc*4);
  float4 w3 = *(const float4*)(Wdc + (size_t)j*256 + 192 + kc*4);
  float cbv = bdc[j];

  __shared__ float hbuf[4][256];
  __shared__ float gbuf[4][64];
  __shared__ float xbuf[4][16];

  const int ub = tid >> 4, ue = tid & 15;
  float creg = 0.f; int myb = 0;
  if (tid < 64){ myb = grp + 8*ub; creg = cT[myb*H_ + slice*EPT_ + ue]; }

  const int tb = tid >> 7, kp = tid & 127;
  const int stage_b = grp + 8*tb;
  int stage_len = 1;
  if (tid < 512) stage_len = slen[stage_b];
  const int ps = (tid - 64) >> 2, pb = (tid - 64) & 3;

  for (int i = 0; i < L_; ++i){
    const int slot = (i - 1) & (RING_ - 1);
    if (i > 0 && tid < 64){
      float gi = gbuf[ub][      ue];
      float gf = gbuf[ub][16 + ue];
      float gg = gbuf[ub][32 + ue];
      float go = gbuf[ub][48 + ue];
      creg = sig_fast(gf)*creg + sig_fast(gi)*tanh_fast(gg);
      float h = sig_fast(go)*tanh_fast(creg);
      xbuf[ub][ue] = h;
      hbuf[ub][slice*EPT_ + ue] = h;
      h2_all[((size_t)(i-1)*B_ + myb)*H_ + slice*EPT_ + ue] = h;
    }
    __syncthreads();  // Bx

    if (i > 0 && tid < 4){
      unsigned long long* dst = rdd + (((size_t)slot*NG_ + grp)*4 + tid)*128 + slice*8;
      const unsigned long long* xs = (const unsigned long long*)xbuf[tid];
#pragma unroll
      for (int k = 0; k < 8; ++k)
        __hip_atomic_store(dst + k, xs[k], __ATOMIC_RELAXED, __HIP_MEMORY_SCOPE_AGENT);
      int* fp = flgd + ((((size_t)slot*NG_ + grp)*NSL_ + slice)*4 + tid)*16;
      __hip_atomic_store(fp, i, __ATOMIC_RELEASE, __HIP_MEMORY_SCOPE_AGENT);
    }
    if (i > 0 && tid >= 64 && tid < 128 && ps != slice){
      const int* fp = flgd + ((((size_t)slot*NG_ + grp)*NSL_ + ps)*4 + pb)*16;
      while (__hip_atomic_load(fp, __ATOMIC_RELAXED, __HIP_MEMORY_SCOPE_AGENT) != i) {}
      __builtin_amdgcn_fence(__ATOMIC_ACQUIRE, "agent");
    }
    __syncthreads();  // B0

    if (tid < 512){
      if (i == 0){
        // h_all fully written by completed enc kernel: plain loads OK
        *(float2*)&hbuf[tb][kp*2] =
            *(const float2*)(h_all + ((size_t)(stage_len-1)*B_ + stage_b)*H_ + kp*2);
      } else if ((kp >> 3) != slice){
        unsigned long long v = __hip_atomic_load(
            rdd + (((size_t)slot*NG_ + grp)*4 + tb)*128 + kp,
            __ATOMIC_RELAXED, __HIP_MEMORY_SCOPE_AGENT);
        *(float2*)&hbuf[tb][kp*2] = __builtin_bit_cast(float2, v);
      }
    }
    __syncthreads();  // B1

#pragma unroll
    for (int b4 = 0; b4 < 4; ++b4){
      float4 h0 = *(const float4*)&hbuf[b4][       kc*4];
      float4 h1 = *(const float4*)&hbuf[b4][ 64 + kc*4];
      float4 h2 = *(const float4*)&hbuf[b4][128 + kc*4];
      float4 h3 = *(const float4*)&hbuf[b4][192 + kc*4];
      float a = dot4(w0,h0) + dot4(w1,h1) + dot4(w2,h2) + dot4(w3,h3);
#pragma unroll
      for (int off = 1; off < 16; off <<= 1) a += __shfl_xor(a, off);
      if (kc == 0) gbuf[b4][rp] = a + cbv;
    }
    __syncthreads();  // B2
  }

  if (tid < 64){
    float gi = gbuf[ub][      ue];
    float gf = gbuf[ub][16 + ue];
    float gg = gbuf[ub][32 + ue];
    float go = gbuf[ub][48 + ue];
    creg = sig_fast(gf)*creg + sig_fast(gi)*tanh_fast(gg);
    float h = sig_fast(go)*tanh_fast(creg);
    h2_all[((size_t)(L_-1)*B_ + myb)*H_ + slice*EPT_ + ue] = h;
  }
}

// ---------------- kproj = masked(enc) @ Wk + bk ----------------
__global__ __launch_bounds__(256) void kproj_kernel(
    const float* __restrict__ h_all, const int* __restrict__ slen,
    const float* __restrict__ Wk, const float* __restrict__ bk,
    float* __restrict__ kp)
{
  __shared__ float wk[256*64];
  const int tid = threadIdx.x;
  const int b = blockIdx.x >> 4, tc = blockIdx.x & 15;
  const int t0 = tc*128;
#pragma unroll
  for (int i=0;i<16;i++){
    int idx = tid + i*256;
    *(float4*)(&wk[idx*4]) = *(const float4*)(Wk + idx*4);
  }
  __syncthreads();
  const int tp = tid>>2, mc = (tid&3)*16;
  const int ta = t0 + tp*2, tb = ta+1;
  const int len = slen[b];
  const bool va = ta < len, vb = tb < len;
  const float* ha = h_all + ((size_t)ta*B_ + b)*H_;
  const float* hb = h_all + ((size_t)tb*B_ + b)*H_;
  float4 A[4], Bv[4];
#pragma unroll
  for (int u=0;u<4;u++){ A[u].x=A[u].y=A[u].z=A[u].w=0.f; Bv[u]=A[u]; }

  for (int k4=0;k4<64;k4++){
    float xa[4], xb[4];
    if (va){ float4 v = *(const float4*)(ha + k4*4); xa[0]=v.x; xa[1]=v.y; xa[2]=v.z; xa[3]=v.w; }
    else   { xa[0]=xa[1]=xa[2]=xa[3]=0.f; }
    if (vb){ float4 v = *(const float4*)(hb + k4*4); xb[0]=v.x; xb[1]=v.y; xb[2]=v.z; xb[3]=v.w; }
    else   { xb[0]=xb[1]=xb[2]=xb[3]=0.f; }
#pragma unroll
    for (int jj=0;jj<4;jj++){
      const float* wr = &wk[(k4*4+jj)*64 + mc];
#pragma unroll
      for (int u=0;u<4;u++){
        float4 wv = *(const float4*)(wr + u*4);
        A[u].x  = fmaf(xa[jj],wv.x,A[u].x);  A[u].y  = fmaf(xa[jj],wv.y,A[u].y);
        A[u].z  = fmaf(xa[jj],wv.z,A[u].z);  A[u].w  = fmaf(xa[jj],wv.w,A[u].w);
        Bv[u].x = fmaf(xb[jj],wv.x,Bv[u].x); Bv[u].y = fmaf(xb[jj],wv.y,Bv[u].y);
        Bv[u].z = fmaf(xb[jj],wv.z,Bv[u].z); Bv[u].w = fmaf(xb[jj],wv.w,Bv[u].w);
      }
    }
  }
#pragma unroll
  for (int u=0;u<4;u++){
    float4 bkv = *(const float4*)(bk + mc + u*4);
    float4 ra, rb;
    ra.x = va ? A[u].x+bkv.x : bkv.x;  ra.y = va ? A[u].y+bkv.y : bkv.y;
    ra.z = va ? A[u].z+bkv.z : bkv.z;  ra.w = va ? A[u].w+bkv.w : bkv.w;
    rb.x = vb ? Bv[u].x+bkv.x : bkv.x; rb.y = vb ? Bv[u].y+bkv.y : bkv.y;
    rb.z = vb ? Bv[u].z+bkv.z : bkv.z; rb.w = vb ? Bv[u].w+bkv.w : bkv.w;
    *(float4*)(kp + ((size_t)b*T_+ta)*M_ + mc + u*4) = ra;
    *(float4*)(kp + ((size_t)b*T_+tb)*M_ + mc + u*4) = rb;
  }
}

// ---------------- attention ----------------
__global__ __launch_bounds__(256) void attn_kernel(
    const float* __restrict__ h2_all, const float* __restrict__ kp,
    const float* __restrict__ WqT, const float* __restrict__ bq,
    const int* __restrict__ slen, float* __restrict__ out)
{
  const int tid = threadIdx.x;
  const int b = blockIdx.x >> 5, scg = blockIdx.x & 31;
  const int s0 = scg*8;
  __shared__ float qL[8][64];
  __shared__ float red[8][4];
  const int wid = tid>>6, lane = tid&63;

  { // q = h2 @ Wq + bq
    const int jj = tid>>5, mh = tid&31;
    const float* hr = h2_all + ((size_t)(s0+jj)*B_ + b)*H_;
    const float* wa = WqT + (size_t)mh*256;
    const float* wb = WqT + (size_t)(mh+32)*256;
    float a0=0.f, a1=0.f;
    for (int k4=0;k4<64;k4++){
      float4 h4 = *(const float4*)(hr + k4*4);
      float4 v0 = *(const float4*)(wa + k4*4);
      float4 v1 = *(const float4*)(wb + k4*4);
      a0 += dot4(h4,v0);
      a1 += dot4(h4,v1);
    }
    qL[jj][mh]    = a0 + bq[mh];
    qL[jj][mh+32] = a1 + bq[mh+32];
  }
  __syncthreads();

  const int len = slen[b];
  float sc_[8][8];
#pragma unroll
  for (int ti=0; ti<8; ti++){
    const int t = ti*256 + tid;
    const float* kr = kp + ((size_t)b*T_ + t)*M_;
    float tmp[8];
#pragma unroll
    for (int jj=0;jj<8;jj++) tmp[jj]=0.f;
#pragma unroll
    for (int u4=0; u4<4; u4++){
      float4 k0 = *(const float4*)(kr + u4*16);
      float4 k1 = *(const float4*)(kr + u4*16 + 4);
      float4 k2 = *(const float4*)(kr + u4*16 + 8);
      float4 k3 = *(const float4*)(kr + u4*16 + 12);
#pragma unroll
      for (int jj=0;jj<8;jj++){
        const float4* q4 = (const float4*)&qL[jj][u4*16];
        tmp[jj] += dot4(k0,q4[0]) + dot4(k1,q4[1]) + dot4(k2,q4[2]) + dot4(k3,q4[3]);
      }
    }
    float bias = (t<len) ? 0.f : -1e9f;
#pragma unroll
    for (int jj=0;jj<8;jj++) sc_[ti][jj] = fmaf(tmp[jj], 0.125f, bias);
  }

  float mx[8];
#pragma unroll
  for (int jj=0;jj<8;jj++){
    float m = sc_[0][jj];
#pragma unroll
    for (int ti=1;ti<8;ti++) m = fmaxf(m, sc_[ti][jj]);
#pragma unroll
    for (int off=1; off<64; off<<=1) m = fmaxf(m, __shfl_xor(m, off));
    if (lane==0) red[jj][wid] = m;
  }
  __syncthreads();
#pragma unroll
  for (int jj=0;jj<8;jj++)
    mx[jj] = fmaxf(fmaxf(red[jj][0],red[jj][1]), fmaxf(red[jj][2],red[jj][3]));
  __syncthreads();
#pragma unroll
  for (int jj=0;jj<8;jj++){
    float s = 0.f;
#pragma unroll
    for (int ti=0;ti<8;ti++){
      float e = __expf(sc_[ti][jj] - mx[jj]);
      sc_[ti][jj] = e;
      s += e;
    }
#pragma unroll
    for (int off=1; off<64; off<<=1) s += __shfl_xor(s, off);
    if (lane==0) red[jj][wid] = s;
  }
  __syncthreads();
#pragma unroll
  for (int jj=0;jj<8;jj++){
    float r = 1.f/(red[jj][0]+red[jj][1]+red[jj][2]+red[jj][3]);
    float* o = out + ((size_t)b*L_ + s0 + jj)*T_;
#pragma unroll
    for (int ti=0;ti<8;ti++) o[ti*256 + tid] = sc_[ti][jj]*r;
  }
}

// ---------------- host ----------------
extern "C" void kernel_launch(void* const* d_in, const int* in_sizes, int n_in,
                              void* d_out, int out_size, void* d_ws, size_t ws_size,
                              hipStream_t stream) {
  (void)in_sizes; (void)n_in; (void)out_size;
  const float* seq  = (const float*)d_in[0];
  const int*   slen = (const int*)  d_in[1];
  const float* Wp   = (const float*)d_in[3];
  const float* bp   = (const float*)d_in[4];
  const float* Wihe = (const float*)d_in[5];
  const float* Whhe = (const float*)d_in[6];
  const float* bihe = (const float*)d_in[7];
  const float* bhhe = (const float*)d_in[8];
  const float* Wihd = (const float*)d_in[9];
  const float* Whhd = (const float*)d_in[10];
  const float* bihd = (const float*)d_in[11];
  const float* bhhd = (const float*)d_in[12];
  const float* Wq   = (const float*)d_in[13];
  const float* bq   = (const float*)d_in[14];
  const float* Wk   = (const float*)d_in[15];
  const float* bk   = (const float*)d_in[16];
  float* out = (float*)d_out;

  char* p = (char*)d_ws;
  auto take = [&](size_t bytes)->char* {
    char* r = p; p += (bytes + 255) & ~(size_t)255; return r;
  };
  float* h2_all = (float*)take((size_t)L_*B_*H_*4);          // 8 MB
  float* kproj  = (float*)take((size_t)B_*T_*M_*4);          // 16 MB
  float* cT     = (float*)take((size_t)B_*H_*4);
  float* W_dc   = (float*)take((size_t)G4_*H_*4);            // 1 MB
  float* Wc0    = (float*)take(G4_*4);
  float* Wc1    = (float*)take(G4_*4);
  float* bc     = (float*)take(G4_*4);
  float* b_dc   = (float*)take(G4_*4);
  float* WqT    = (float*)take((size_t)M_*H_*4);
  // data rings: [slot][grp][batch][256] floats as u64 pairs
  unsigned long long* rde = (unsigned long long*)take((size_t)RING_*NG_*4*128*8);   // 256 KB
  unsigned long long* rdd = (unsigned long long*)take((size_t)RING_*NG_*4*128*8);   // 256 KB
  // flag rings: [slot][grp][slice][batch] x 16 ints (64B padded)
  int* flge = (int*)take((size_t)RING_*NG_*NSL_*4*16*4);                            // 256 KB
  int* flgd = (int*)take((size_t)RING_*NG_*NSL_*4*16*4);                            // 256 KB

  size_t used = (size_t)(p - (char*)d_ws);
  float* h_all;
  if (ws_size >= used + (size_t)T_*B_*H_*4) {
    h_all = (float*)take((size_t)T_*B_*H_*4);                // 64 MB
  } else {
    h_all = out;  // d_out is exactly T_*B_*H_ floats; dead before attn writes
  }

  // zero the flag rings (tags are 1..T so 0 never matches); data rings need no init
  hipMemsetAsync(flge, 0, (size_t)RING_*NG_*NSL_*4*16*4, stream);
  hipMemsetAsync(flgd, 0, (size_t)RING_*NG_*NSL_*4*16*4, stream);

  prep_wdc  <<<G4_*H_/256, 256, 0, stream>>>(Wihd, Whhd, W_dc);
  prep_small<<<68, 256, 0, stream>>>(Wp, bp, Wihe, bihe, bhhe, bihd, bhhd, Wq,
                                     Wc0, Wc1, bc, b_dc, WqT);
  enc_kernel<<<NG_*NSL_, 1024, 0, stream>>>(seq, slen, Whhe, Wc0, Wc1, bc,
                                            h_all, cT, rde, flge);
  kproj_kernel<<<B_*16, 256, 0, stream>>>(h_all, slen, Wk, bk, kproj);
  dec_kernel<<<NG_*NSL_, 1024, 0, stream>>>(slen, W_dc, b_dc, h_all, cT,
                                            h2_all, rdd, flgd);
  attn_kernel<<<B_*32, 256, 0, stream>>>(h2_all, kproj, WqT, bq, slen, out);
}

// Round 6
// 7001.997 us; speedup vs baseline: 1.7023x; 1.7023x over previous
//
#include <hip/hip_runtime.h>
#include <stdint.h>

#define B_ 32
#define T_ 2048
#define H_ 256
#define M_ 64
#define L_ 256
#define G4_ 1024     // 4*H gate rows

#define NG_ 8        // batch groups (4 batches each)
#define NSL_ 16      // hidden slices per group
#define EPT_ 16      // h elements per slice
#define RING_ 8      // ring slots; skew <=2 so reuse distance 8 is safe

__device__ __forceinline__ float sig_fast(float x){ return 1.f/(1.f+__expf(-x)); }
__device__ __forceinline__ float tanh_fast(float x){ return 2.f/(1.f+__expf(-2.f*x)) - 1.f; }
__device__ __forceinline__ float dot4(float4 a, float4 b){
  return fmaf(a.x,b.x, fmaf(a.y,b.y, fmaf(a.z,b.z, a.w*b.w)));
}

// ---------------- prep kernels ----------------
__global__ void prep_wdc(const float* __restrict__ a, const float* __restrict__ b,
                         float* __restrict__ o){
  int i = blockIdx.x*256 + threadIdx.x;
  o[i] = a[i] + b[i];
}

__global__ void prep_small(const float* __restrict__ Wp, const float* __restrict__ bp,
                           const float* __restrict__ Wihe, const float* __restrict__ bihe,
                           const float* __restrict__ bhhe, const float* __restrict__ bihd,
                           const float* __restrict__ bhhd, const float* __restrict__ Wq,
                           float* __restrict__ Wc0, float* __restrict__ Wc1,
                           float* __restrict__ bc, float* __restrict__ bdc,
                           float* __restrict__ WqT){
  int idx = blockIdx.x*256 + threadIdx.x;
  if (idx < 16384){                 // WqT[m][k] = Wq[k][m]
    int m = idx >> 8, k = idx & 255;
    WqT[m*256 + k] = Wq[k*64 + m];
  } else if (idx < 16384 + 1024){   // fused input coeffs per gate row
    int j = idx - 16384;
    const float* wr = Wihe + j*256;
    float a0=0.f, a1=0.f, ab=0.f;
    for (int e=0;e<256;e++){
      float w = wr[e];
      a0 = fmaf(Wp[e],     w, a0);
      a1 = fmaf(Wp[256+e], w, a1);
      ab = fmaf(bp[e],     w, ab);
    }
    Wc0[j] = a0; Wc1[j] = a1;
    bc[j]  = ab + bihe[j] + bhhe[j];
    bdc[j] = bihd[j] + bhhd[j];
  }
}

// ---------------- encoder LSTM (persistent; fused-packet ring, batched polls) ----------------
__global__ __launch_bounds__(1024) void enc_kernel(
    const float* __restrict__ seq, const int* __restrict__ slen,
    const float* __restrict__ Whh,
    const float* __restrict__ Wc0, const float* __restrict__ Wc1,
    const float* __restrict__ bc,
    float* __restrict__ h_all, float* __restrict__ cT,
    unsigned long long* __restrict__ ring)
{
  const int tid = threadIdx.x;
  const int grp = blockIdx.x & 7, slice = blockIdx.x >> 3;
  const int rp = tid >> 4, kc = tid & 15;
  const int j = ((rp >> 4) << 8) + slice*EPT_ + (rp & 15);   // gate*256 + slice*16 + elem
  float4 w0 = *(const float4*)(Whh + (size_t)j*256 +   0 + kc*4);
  float4 w1 = *(const float4*)(Whh + (size_t)j*256 +  64 + kc*4);
  float4 w2 = *(const float4*)(Whh + (size_t)j*256 + 128 + kc*4);
  float4 w3 = *(const float4*)(Whh + (size_t)j*256 + 192 + kc*4);
  float c0 = Wc0[j], c1 = Wc1[j], cbv = bc[j];

  __shared__ float hbuf[4][256];
  __shared__ float sbuf[4][2];
  __shared__ float gbuf[4][64];

  const int ub = tid >> 4, ue = tid & 15;       // updater mapping (tid<64)
  float creg = 0.f;
  int myb = 0, mylen = -1;
  if (tid < 64){ myb = grp + 8*ub; mylen = slen[myb]; }

  const bool poller = (tid < 256) && ((tid >> 4) != slice);
  unsigned long long* ringg = ring + (size_t)grp * (RING_*1024);

  for (int t = 0; t < T_; ++t){
    // ---- per-step seq inputs (issued first; overlaps polls) ----
    if (tid < 8) sbuf[tid>>1][tid&1] = seq[((size_t)(grp + 8*(tid>>1))*T_ + t)*2 + (tid&1)];

    // ---- stage h_{t-1}: 240 pollers x 4 fused {tag,h} packets ----
    if (t == 0){
      hbuf[tid>>8][tid&255] = 0.f;
    } else if (poller){
      const unsigned long long* bp_ = ringg + (size_t)((t-1)&(RING_-1))*1024 + tid;
      const unsigned tg = (unsigned)t;
      unsigned got = 0;
      do {
        unsigned long long v0 = __hip_atomic_load(bp_+  0, __ATOMIC_RELAXED, __HIP_MEMORY_SCOPE_AGENT);
        unsigned long long v1 = __hip_atomic_load(bp_+256, __ATOMIC_RELAXED, __HIP_MEMORY_SCOPE_AGENT);
        unsigned long long v2 = __hip_atomic_load(bp_+512, __ATOMIC_RELAXED, __HIP_MEMORY_SCOPE_AGENT);
        unsigned long long v3 = __hip_atomic_load(bp_+768, __ATOMIC_RELAXED, __HIP_MEMORY_SCOPE_AGENT);
        if (!(got&1u) && (unsigned)(v0>>32)==tg){ hbuf[0][tid] = __uint_as_float((unsigned)v0); got|=1u; }
        if (!(got&2u) && (unsigned)(v1>>32)==tg){ hbuf[1][tid] = __uint_as_float((unsigned)v1); got|=2u; }
        if (!(got&4u) && (unsigned)(v2>>32)==tg){ hbuf[2][tid] = __uint_as_float((unsigned)v2); got|=4u; }
        if (!(got&8u) && (unsigned)(v3>>32)==tg){ hbuf[3][tid] = __uint_as_float((unsigned)v3); got|=8u; }
      } while (got != 15u);
    }
    __syncthreads();  // B1: hbuf/sbuf ready

    // ---- compute: one gate row per thread, K split over 16 lanes ----
#pragma unroll
    for (int i = 0; i < 4; ++i){
      float4 h0 = *(const float4*)&hbuf[i][       kc*4];
      float4 h1 = *(const float4*)&hbuf[i][ 64 + kc*4];
      float4 h2 = *(const float4*)&hbuf[i][128 + kc*4];
      float4 h3 = *(const float4*)&hbuf[i][192 + kc*4];
      float a = dot4(w0,h0) + dot4(w1,h1) + dot4(w2,h2) + dot4(w3,h3);
#pragma unroll
      for (int off = 1; off < 16; off <<= 1) a += __shfl_xor(a, off);
      if (kc == 0)
        gbuf[i][rp] = fmaf(sbuf[i][0], c0, fmaf(sbuf[i][1], c1, a + cbv));
    }
    __syncthreads();  // B2: gbuf ready

    // ---- update + publish (tid<64: 4 batches x 16 elems) ----
    if (tid < 64){
      float gi = gbuf[ub][      ue];
      float gf = gbuf[ub][16 + ue];
      float gg = gbuf[ub][32 + ue];
      float go = gbuf[ub][48 + ue];
      creg = sig_fast(gf)*creg + sig_fast(gi)*tanh_fast(gg);
      float h = sig_fast(go)*tanh_fast(creg);
      unsigned long long pk = ((unsigned long long)(unsigned)(t+1) << 32)
                            | (unsigned long long)__float_as_uint(h);
      __hip_atomic_store(ringg + (size_t)(t & (RING_-1))*1024 + ub*256 + slice*EPT_ + ue,
                         pk, __ATOMIC_RELAXED, __HIP_MEMORY_SCOPE_AGENT);
      hbuf[ub][slice*EPT_ + ue] = h;                            // own-slice short-circuit
      h_all[((size_t)t*B_ + myb)*H_ + slice*EPT_ + ue] = h;     // off critical path
      if (t == mylen - 1) cT[myb*H_ + slice*EPT_ + ue] = creg;
    }
    // next-iter staging writes only remote hbuf regions; separated by B1
  }
}

// ---------------- decoder LSTM (x == h, folded weights) ----------------
__global__ __launch_bounds__(1024) void dec_kernel(
    const int* __restrict__ slen,
    const float* __restrict__ Wdc, const float* __restrict__ bdc,
    const float* __restrict__ h_all, const float* __restrict__ cT,
    float* __restrict__ h2_all, unsigned long long* __restrict__ ring)
{
  const int tid = threadIdx.x;
  const int grp = blockIdx.x & 7, slice = blockIdx.x >> 3;
  const int rp = tid >> 4, kc = tid & 15;
  const int j = ((rp >> 4) << 8) + slice*EPT_ + (rp & 15);
  float4 w0 = *(const float4*)(Wdc + (size_t)j*256 +   0 + kc*4);
  float4 w1 = *(const float4*)(Wdc + (size_t)j*256 +  64 + kc*4);
  float4 w2 = *(const float4*)(Wdc + (size_t)j*256 + 128 + kc*4);
  float4 w3 = *(const float4*)(Wdc + (size_t)j*256 + 192 + kc*4);
  float cbv = bdc[j];

  __shared__ float hbuf[4][256];
  __shared__ float gbuf[4][64];

  const int ub = tid >> 4, ue = tid & 15;
  float creg = 0.f; int myb = 0;
  if (tid < 64){ myb = grp + 8*ub; creg = cT[myb*H_ + slice*EPT_ + ue]; }

  const int tb = tid >> 7, kp = tid & 127;      // s==0 bulk-stage mapping (tid<512)
  const int stage_b = grp + 8*tb;
  int stage_len = 1;
  if (tid < 512) stage_len = slen[stage_b];

  const bool poller = (tid < 256) && ((tid >> 4) != slice);
  unsigned long long* ringg = ring + (size_t)grp * (RING_*1024);

  for (int s = 0; s < L_; ++s){
    if (s == 0){
      if (tid < 512)   // h_all fully written by completed enc kernel: plain loads OK
        *(float2*)&hbuf[tb][kp*2] =
            *(const float2*)(h_all + ((size_t)(stage_len-1)*B_ + stage_b)*H_ + kp*2);
    } else if (poller){
      const unsigned long long* bp_ = ringg + (size_t)((s-1)&(RING_-1))*1024 + tid;
      const unsigned tg = (unsigned)s;
      unsigned got = 0;
      do {
        unsigned long long v0 = __hip_atomic_load(bp_+  0, __ATOMIC_RELAXED, __HIP_MEMORY_SCOPE_AGENT);
        unsigned long long v1 = __hip_atomic_load(bp_+256, __ATOMIC_RELAXED, __HIP_MEMORY_SCOPE_AGENT);
        unsigned long long v2 = __hip_atomic_load(bp_+512, __ATOMIC_RELAXED, __HIP_MEMORY_SCOPE_AGENT);
        unsigned long long v3 = __hip_atomic_load(bp_+768, __ATOMIC_RELAXED, __HIP_MEMORY_SCOPE_AGENT);
        if (!(got&1u) && (unsigned)(v0>>32)==tg){ hbuf[0][tid] = __uint_as_float((unsigned)v0); got|=1u; }
        if (!(got&2u) && (unsigned)(v1>>32)==tg){ hbuf[1][tid] = __uint_as_float((unsigned)v1); got|=2u; }
        if (!(got&4u) && (unsigned)(v2>>32)==tg){ hbuf[2][tid] = __uint_as_float((unsigned)v2); got|=4u; }
        if (!(got&8u) && (unsigned)(v3>>32)==tg){ hbuf[3][tid] = __uint_as_float((unsigned)v3); got|=8u; }
      } while (got != 15u);
    }
    __syncthreads();  // B1

#pragma unroll
    for (int i = 0; i < 4; ++i){
      float4 h0 = *(const float4*)&hbuf[i][       kc*4];
      float4 h1 = *(const float4*)&hbuf[i][ 64 + kc*4];
      float4 h2 = *(const float4*)&hbuf[i][128 + kc*4];
      float4 h3 = *(const float4*)&hbuf[i][192 + kc*4];
      float a = dot4(w0,h0) + dot4(w1,h1) + dot4(w2,h2) + dot4(w3,h3);
#pragma unroll
      for (int off = 1; off < 16; off <<= 1) a += __shfl_xor(a, off);
      if (kc == 0) gbuf[i][rp] = a + cbv;
    }
    __syncthreads();  // B2

    if (tid < 64){
      float gi = gbuf[ub][      ue];
      float gf = gbuf[ub][16 + ue];
      float gg = gbuf[ub][32 + ue];
      float go = gbuf[ub][48 + ue];
      creg = sig_fast(gf)*creg + sig_fast(gi)*tanh_fast(gg);
      float h = sig_fast(go)*tanh_fast(creg);
      unsigned long long pk = ((unsigned long long)(unsigned)(s+1) << 32)
                            | (unsigned long long)__float_as_uint(h);
      __hip_atomic_store(ringg + (size_t)(s & (RING_-1))*1024 + ub*256 + slice*EPT_ + ue,
                         pk, __ATOMIC_RELAXED, __HIP_MEMORY_SCOPE_AGENT);
      hbuf[ub][slice*EPT_ + ue] = h;                            // own-slice short-circuit
      h2_all[((size_t)s*B_ + myb)*H_ + slice*EPT_ + ue] = h;
    }
  }
}

// ---------------- kproj = masked(enc) @ Wk + bk ----------------
__global__ __launch_bounds__(256) void kproj_kernel(
    const float* __restrict__ h_all, const int* __restrict__ slen,
    const float* __restrict__ Wk, const float* __restrict__ bk,
    float* __restrict__ kp)
{
  __shared__ float wk[256*64];
  const int tid = threadIdx.x;
  const int b = blockIdx.x >> 4, tc = blockIdx.x & 15;
  const int t0 = tc*128;
#pragma unroll
  for (int i=0;i<16;i++){
    int idx = tid + i*256;
    *(float4*)(&wk[idx*4]) = *(const float4*)(Wk + idx*4);
  }
  __syncthreads();
  const int tp = tid>>2, mc = (tid&3)*16;
  const int ta = t0 + tp*2, tb = ta+1;
  const int len = slen[b];
  const bool va = ta < len, vb = tb < len;
  const float* ha = h_all + ((size_t)ta*B_ + b)*H_;
  const float* hb = h_all + ((size_t)tb*B_ + b)*H_;
  float4 A[4], Bv[4];
#pragma unroll
  for (int u=0;u<4;u++){ A[u].x=A[u].y=A[u].z=A[u].w=0.f; Bv[u]=A[u]; }

  for (int k4=0;k4<64;k4++){
    float xa[4], xb[4];
    if (va){ float4 v = *(const float4*)(ha + k4*4); xa[0]=v.x; xa[1]=v.y; xa[2]=v.z; xa[3]=v.w; }
    else   { xa[0]=xa[1]=xa[2]=xa[3]=0.f; }
    if (vb){ float4 v = *(const float4*)(hb + k4*4); xb[0]=v.x; xb[1]=v.y; xb[2]=v.z; xb[3]=v.w; }
    else   { xb[0]=xb[1]=xb[2]=xb[3]=0.f; }
#pragma unroll
    for (int jj=0;jj<4;jj++){
      const float* wr = &wk[(k4*4+jj)*64 + mc];
#pragma unroll
      for (int u=0;u<4;u++){
        float4 wv = *(const float4*)(wr + u*4);
        A[u].x  = fmaf(xa[jj],wv.x,A[u].x);  A[u].y  = fmaf(xa[jj],wv.y,A[u].y);
        A[u].z  = fmaf(xa[jj],wv.z,A[u].z);  A[u].w  = fmaf(xa[jj],wv.w,A[u].w);
        Bv[u].x = fmaf(xb[jj],wv.x,Bv[u].x); Bv[u].y = fmaf(xb[jj],wv.y,Bv[u].y);
        Bv[u].z = fmaf(xb[jj],wv.z,Bv[u].z); Bv[u].w = fmaf(xb[jj],wv.w,Bv[u].w);
      }
    }
  }
#pragma unroll
  for (int u=0;u<4;u++){
    float4 bkv = *(const float4*)(bk + mc + u*4);
    float4 ra, rb;
    ra.x = va ? A[u].x+bkv.x : bkv.x;  ra.y = va ? A[u].y+bkv.y : bkv.y;
    ra.z = va ? A[u].z+bkv.z : bkv.z;  ra.w = va ? A[u].w+bkv.w : bkv.w;
    rb.x = vb ? Bv[u].x+bkv.x : bkv.x; rb.y = vb ? Bv[u].y+bkv.y : bkv.y;
    rb.z = vb ? Bv[u].z+bkv.z : bkv.z; rb.w = vb ? Bv[u].w+bkv.w : bkv.w;
    *(float4*)(kp + ((size_t)b*T_+ta)*M_ + mc + u*4) = ra;
    *(float4*)(kp + ((size_t)b*T_+tb)*M_ + mc + u*4) = rb;
  }
}

// ---------------- attention ----------------
__global__ __launch_bounds__(256) void attn_kernel(
    const float* __restrict__ h2_all, const float* __restrict__ kp,
    const float* __restrict__ WqT, const float* __restrict__ bq,
    const int* __restrict__ slen, float* __restrict__ out)
{
  const int tid = threadIdx.x;
  const int b = blockIdx.x >> 5, scg = blockIdx.x & 31;
  const int s0 = scg*8;
  __shared__ float qL[8][64];
  __shared__ float red[8][4];
  const int wid = tid>>6, lane = tid&63;

  { // q = h2 @ Wq + bq
    const int jj = tid>>5, mh = tid&31;
    const float* hr = h2_all + ((size_t)(s0+jj)*B_ + b)*H_;
    const float* wa = WqT + (size_t)mh*256;
    const float* wb = WqT + (size_t)(mh+32)*256;
    float a0=0.f, a1=0.f;
    for (int k4=0;k4<64;k4++){
      float4 h4 = *(const float4*)(hr + k4*4);
      float4 v0 = *(const float4*)(wa + k4*4);
      float4 v1 = *(const float4*)(wb + k4*4);
      a0 += dot4(h4,v0);
      a1 += dot4(h4,v1);
    }
    qL[jj][mh]    = a0 + bq[mh];
    qL[jj][mh+32] = a1 + bq[mh+32];
  }
  __syncthreads();

  const int len = slen[b];
  float sc_[8][8];
#pragma unroll
  for (int ti=0; ti<8; ti++){
    const int t = ti*256 + tid;
    const float* kr = kp + ((size_t)b*T_ + t)*M_;
    float tmp[8];
#pragma unroll
    for (int jj=0;jj<8;jj++) tmp[jj]=0.f;
#pragma unroll
    for (int u4=0; u4<4; u4++){
      float4 k0 = *(const float4*)(kr + u4*16);
      float4 k1 = *(const float4*)(kr + u4*16 + 4);
      float4 k2 = *(const float4*)(kr + u4*16 + 8);
      float4 k3 = *(const float4*)(kr + u4*16 + 12);
#pragma unroll
      for (int jj=0;jj<8;jj++){
        const float4* q4 = (const float4*)&qL[jj][u4*16];
        tmp[jj] += dot4(k0,q4[0]) + dot4(k1,q4[1]) + dot4(k2,q4[2]) + dot4(k3,q4[3]);
      }
    }
    float bias = (t<len) ? 0.f : -1e9f;
#pragma unroll
    for (int jj=0;jj<8;jj++) sc_[ti][jj] = fmaf(tmp[jj], 0.125f, bias);
  }

  float mx[8];
#pragma unroll
  for (int jj=0;jj<8;jj++){
    float m = sc_[0][jj];
#pragma unroll
    for (int ti=1;ti<8;ti++) m = fmaxf(m, sc_[ti][jj]);
#pragma unroll
    for (int off=1; off<64; off<<=1) m = fmaxf(m, __shfl_xor(m, off));
    if (lane==0) red[jj][wid] = m;
  }
  __syncthreads();
#pragma unroll
  for (int jj=0;jj<8;jj++)
    mx[jj] = fmaxf(fmaxf(red[jj][0],red[jj][1]), fmaxf(red[jj][2],red[jj][3]));
  __syncthreads();
#pragma unroll
  for (int jj=0;jj<8;jj++){
    float s = 0.f;
#pragma unroll
    for (int ti=0;ti<8;ti++){
      float e = __expf(sc_[ti][jj] - mx[jj]);
      sc_[ti][jj] = e;
      s += e;
    }
#pragma unroll
    for (int off=1; off<64; off<<=1) s += __shfl_xor(s, off);
    if (lane==0) red[jj][wid] = s;
  }
  __syncthreads();
#pragma unroll
  for (int jj=0;jj<8;jj++){
    float r = 1.f/(red[jj][0]+red[jj][1]+red[jj][2]+red[jj][3]);
    float* o = out + ((size_t)b*L_ + s0 + jj)*T_;
#pragma unroll
    for (int ti=0;ti<8;ti++) o[ti*256 + tid] = sc_[ti][jj]*r;
  }
}

// ---------------- host ----------------
extern "C" void kernel_launch(void* const* d_in, const int* in_sizes, int n_in,
                              void* d_out, int out_size, void* d_ws, size_t ws_size,
                              hipStream_t stream) {
  (void)in_sizes; (void)n_in; (void)out_size;
  const float* seq  = (const float*)d_in[0];
  const int*   slen = (const int*)  d_in[1];
  const float* Wp   = (const float*)d_in[3];
  const float* bp   = (const float*)d_in[4];
  const float* Wihe = (const float*)d_in[5];
  const float* Whhe = (const float*)d_in[6];
  const float* bihe = (const float*)d_in[7];
  const float* bhhe = (const float*)d_in[8];
  const float* Wihd = (const float*)d_in[9];
  const float* Whhd = (const float*)d_in[10];
  const float* bihd = (const float*)d_in[11];
  const float* bhhd = (const float*)d_in[12];
  const float* Wq   = (const float*)d_in[13];
  const float* bq   = (const float*)d_in[14];
  const float* Wk   = (const float*)d_in[15];
  const float* bk   = (const float*)d_in[16];
  float* out = (float*)d_out;

  char* p = (char*)d_ws;
  auto take = [&](size_t bytes)->char* {
    char* r = p; p += (bytes + 255) & ~(size_t)255; return r;
  };
  float* h2_all = (float*)take((size_t)L_*B_*H_*4);          // 8 MB
  float* kproj  = (float*)take((size_t)B_*T_*M_*4);          // 16 MB
  float* cT     = (float*)take((size_t)B_*H_*4);
  float* W_dc   = (float*)take((size_t)G4_*H_*4);            // 1 MB
  float* Wc0    = (float*)take(G4_*4);
  float* Wc1    = (float*)take(G4_*4);
  float* bc     = (float*)take(G4_*4);
  float* b_dc   = (float*)take(G4_*4);
  float* WqT    = (float*)take((size_t)M_*H_*4);
  unsigned long long* ring_e = (unsigned long long*)take((size_t)NG_*RING_*1024*8); // 512 KB
  unsigned long long* ring_d = (unsigned long long*)take((size_t)NG_*RING_*1024*8); // 512 KB

  size_t used = (size_t)(p - (char*)d_ws);
  float* h_all;
  if (ws_size >= used + (size_t)T_*B_*H_*4) {
    h_all = (float*)take((size_t)T_*B_*H_*4);                // 64 MB
  } else {
    h_all = out;  // d_out is exactly T_*B_*H_ floats; dead before attn writes
  }

  // zero the tag rings (tags are 1..T so 0 never matches); re-zeroed every replay
  hipMemsetAsync(ring_e, 0, (size_t)NG_*RING_*1024*8, stream);
  hipMemsetAsync(ring_d, 0, (size_t)NG_*RING_*1024*8, stream);

  prep_wdc  <<<G4_*H_/256, 256, 0, stream>>>(Wihd, Whhd, W_dc);
  prep_small<<<68, 256, 0, stream>>>(Wp, bp, Wihe, bihe, bhhe, bihd, bhhd, Wq,
                                     Wc0, Wc1, bc, b_dc, WqT);
  enc_kernel<<<NG_*NSL_, 1024, 0, stream>>>(seq, slen, Whhe, Wc0, Wc1, bc,
                                            h_all, cT, ring_e);
  kproj_kernel<<<B_*16, 256, 0, stream>>>(h_all, slen, Wk, bk, kproj);
  dec_kernel<<<NG_*NSL_, 1024, 0, stream>>>(slen, W_dc, b_dc, h_all, cT,
                                            h2_all, ring_d);
  attn_kernel<<<B_*32, 256, 0, stream>>>(h2_all, kproj, WqT, bq, slen, out);
}